// Round 16
// baseline (60.894 us; speedup 1.0000x reference)
//
#include <hip/hip_runtime.h>
#include <hip/hip_bf16.h>

#define LQ 4096
#define DD 64
#define NB 4
#define NTOT ((size_t)NB * LQ * DD)
#define NROW ((size_t)NB * LQ)

typedef __attribute__((ext_vector_type(4))) float f32x4;
typedef __attribute__((ext_vector_type(8))) short short8;
typedef __attribute__((ext_vector_type(4))) short short4v;
typedef __attribute__((ext_vector_type(2))) unsigned int uint2v;
typedef __attribute__((ext_vector_type(4))) unsigned short ushort4v;

static __device__ __forceinline__ unsigned short f2bf(float x) {
  __hip_bfloat16 h = __float2bfloat16(x);
  return __builtin_bit_cast(unsigned short, h);
}
static __device__ __forceinline__ float bf2f(unsigned short u) {
  unsigned int v = ((unsigned int)u) << 16;
  return __builtin_bit_cast(float, v);
}
static __device__ __forceinline__ float ex2(float x) { return __builtin_amdgcn_exp2f(x); }

static __device__ __forceinline__ f32x4 mfma16(short4v a, short4v b, f32x4 c) {
#if __has_builtin(__builtin_amdgcn_mfma_f32_16x16x16bf16_1k)
  return __builtin_amdgcn_mfma_f32_16x16x16bf16_1k(a, b, c, 0, 0, 0);
#else
  asm volatile("v_mfma_f32_16x16x16_bf16 %0, %1, %2, %0"
               : "+v"(c) : "v"(a), "v"(b));
  return c;
#endif
}

// async global->LDS, 16B per lane, dest = ldsbase + lane*16
static __device__ __forceinline__ void gl_lds16(const unsigned short* g, unsigned short* l) {
  __builtin_amdgcn_global_load_lds(
      (const __attribute__((address_space(1))) unsigned int*)g,
      (__attribute__((address_space(3))) unsigned int*)l, 16, 0, 0);
}

// score scale folded into log2 domain: s2 = T * (0.125 * log2(e))
#define C1 0.18033688011112042f

// ---------------------------------------------------------------------------
// prep: pure cast Q,K,V -> bf16 (layouts unchanged, [b][i][d])
// ---------------------------------------------------------------------------
__global__ __launch_bounds__(256) void prep_kernel(
    const float* __restrict__ q, const float* __restrict__ k,
    const float* __restrict__ v,
    unsigned short* __restrict__ Qb, unsigned short* __restrict__ Kb,
    unsigned short* __restrict__ Vb)
{
  const int arr = blockIdx.x >> 9;
  const size_t off = (((size_t)(blockIdx.x & 511)) * 256 + threadIdx.x) * 8;
  const float* s = arr == 0 ? q : arr == 1 ? k : v;
  unsigned short* d = arr == 0 ? Qb : arr == 1 ? Kb : Vb;
  const f32x4 x0 = *(const f32x4*)(s + off);
  const f32x4 x1 = *(const f32x4*)(s + off + 4);
  ushort4v o0 = { f2bf(x0[0]), f2bf(x0[1]), f2bf(x0[2]), f2bf(x0[3]) };
  ushort4v o1 = { f2bf(x1[0]), f2bf(x1[1]), f2bf(x1[2]), f2bf(x1[3]) };
  *(ushort4v*)(d + off) = o0;
  *(ushort4v*)(d + off + 4) = o1;
}

// ---------------------------------------------------------------------------
// stats (round-11 exact): part_ls[jc][b*LQ+i] = sum_{j in chunk} exp2(T*C1)
// grid: NB*16*8 = 512 blocks of 256. Block: i-tile 256, j-chunk 512.
// ---------------------------------------------------------------------------
__global__ __launch_bounds__(256, 2) void stats_kernel(
    const unsigned short* __restrict__ Qb, const unsigned short* __restrict__ Kb,
    float* __restrict__ part_ls)
{
  __shared__ __align__(16) unsigned short stK[3][2048];
  const int bx = blockIdx.x;
  const int jc = bx & 7, it = (bx >> 3) & 15, b = bx >> 7;
  const int tid = threadIdx.x, w = tid >> 6, lane = tid & 63;
  const int l15 = lane & 15, g = lane >> 4;
  const int i0 = it * 256 + w * 64;
  const int jbase = jc * 512;
  const unsigned short* Kbase = Kb + (size_t)b * LQ * DD;

  short8 aq[4][2];
#pragma unroll
  for (int is = 0; is < 4; ++is)
#pragma unroll
    for (int kh = 0; kh < 2; ++kh)
      aq[is][kh] = *(const short8*)(Qb + ((size_t)b * LQ + i0 + is * 16 + l15) * DD + kh * 32 + g * 8);

  float ls[4][4];
#pragma unroll
  for (int is = 0; is < 4; ++is)
#pragma unroll
    for (int qq = 0; qq < 4; ++qq) ls[is][qq] = 0.f;

  const int srow = w * 8 + (lane >> 3);
  const int scol = ((lane & 7) ^ (lane >> 3)) << 3;

  gl_lds16(Kbase + (size_t)(jbase + srow) * DD + scol, &stK[0][w * 512]);
  gl_lds16(Kbase + (size_t)(jbase + 32 + srow) * DD + scol, &stK[1][w * 512]);
  asm volatile("s_waitcnt vmcnt(1)" ::: "memory");
  __builtin_amdgcn_s_barrier();

  for (int itr = 0; itr < 16; ++itr) {
    const int cur = itr % 3;
    const int tn = (itr + 2 < 16) ? itr + 2 : 15;
    gl_lds16(Kbase + (size_t)(jbase + tn * 32 + srow) * DD + scol, &stK[(itr + 2) % 3][w * 512]);

    short8 kf[2][2];
#pragma unroll
    for (int jsub = 0; jsub < 2; ++jsub)
#pragma unroll
      for (int kh = 0; kh < 2; ++kh) {
        const int row = jsub * 16 + l15;
        kf[jsub][kh] = *(const short8*)(&stK[cur][row * 64 + (((kh * 4 + g) ^ (l15 & 7)) << 3)]);
      }
#pragma unroll
    for (int is = 0; is < 4; ++is)
#pragma unroll
      for (int jsub = 0; jsub < 2; ++jsub) {
        f32x4 tt = __builtin_amdgcn_mfma_f32_16x16x32_bf16(
            aq[is][0], kf[jsub][0], (f32x4){0.f, 0.f, 0.f, 0.f}, 0, 0, 0);
        tt = __builtin_amdgcn_mfma_f32_16x16x32_bf16(aq[is][1], kf[jsub][1], tt, 0, 0, 0);
#pragma unroll
        for (int qq = 0; qq < 4; ++qq) ls[is][qq] += ex2(tt[qq] * C1);
      }
    asm volatile("s_waitcnt vmcnt(1)" ::: "memory");
    __builtin_amdgcn_s_barrier();
  }
#pragma unroll
  for (int mask = 1; mask <= 8; mask <<= 1)
#pragma unroll
    for (int is = 0; is < 4; ++is)
#pragma unroll
      for (int qq = 0; qq < 4; ++qq) ls[is][qq] += __shfl_xor(ls[is][qq], mask, 64);
  if (l15 == 0) {
#pragma unroll
    for (int is = 0; is < 4; ++is)
#pragma unroll
      for (int qq = 0; qq < 4; ++qq)
        part_ls[(size_t)jc * NROW + b * LQ + i0 + is * 16 + g * 4 + qq] = ls[is][qq];
  }
}

// ---------------------------------------------------------------------------
// combine: Vs[r][d] = Vb[r][d] / l_r ,  l_r = sum_{jc<8} part_ls[jc][r]
// ---------------------------------------------------------------------------
__global__ __launch_bounds__(256) void combine_kernel(
    const float* __restrict__ part_ls, const unsigned short* __restrict__ Vb,
    unsigned short* __restrict__ Vs)
{
  const size_t base = ((size_t)blockIdx.x * 256 + threadIdx.x) * 8;
  const int r = (int)(base >> 6);
  float l = 0.f;
#pragma unroll
  for (int jc = 0; jc < 8; ++jc) l += part_ls[(size_t)jc * NROW + r];
  const float s = 1.0f / l;
  const ushort4v a = *(const ushort4v*)(Vb + base);
  const ushort4v c = *(const ushort4v*)(Vb + base + 4);
  ushort4v oa = { f2bf(bf2f(a[0]) * s), f2bf(bf2f(a[1]) * s),
                  f2bf(bf2f(a[2]) * s), f2bf(bf2f(a[3]) * s) };
  ushort4v oc = { f2bf(bf2f(c[0]) * s), f2bf(bf2f(c[1]) * s),
                  f2bf(bf2f(c[2]) * s), f2bf(bf2f(c[3]) * s) };
  *(ushort4v*)(Vs + base) = oa;
  *(ushort4v*)(Vs + base + 4) = oc;
}

// ---------------------------------------------------------------------------
// attn_out: out[j][d] = sum_i exp2(T[j,i]*C1) * Vs[i][d]   (fp32, no split)
// grid: NB*64 = 256 blocks of 1024 (16 waves = 4 waves/SIMD). Wave
// (p=w>>1, sub=w&1): j-half jt*64+sub*32 (2 js), i-range [p*512,+512) as
// 32 iters of 16 rows. PRIVATE DOUBLE-BUFFERED stage (2 x 4KB/wave,
// 128 KB total): prefetch 2 tiles ahead, counted vmcnt(4) at iter top
// (never 0 except last iter). Swapped QK keeps P in registers; PV via
// K=16 MFMAs with single-tr-read V frags. No block barriers in loop.
// ---------------------------------------------------------------------------
__global__ __launch_bounds__(1024, 4) void attn_out_kernel(
    const unsigned short* __restrict__ Qb, const unsigned short* __restrict__ Kb,
    const unsigned short* __restrict__ Vs, float* __restrict__ out)
{
  __shared__ __align__(16) unsigned short stage[16][2][2048]; // 128 KB [wave][buf][Q 1K|V 1K]

  const int bx = blockIdx.x;
  const int jt = bx & 63;
  const int b  = bx >> 6;
  const int tid = threadIdx.x, w = tid >> 6, lane = tid & 63;
  const int p = w >> 1, sub = w & 1;
  const int l15 = lane & 15, g = lane >> 4;
  const int j0 = jt * 64 + sub * 32;

  const unsigned short* Qbase = Qb + (size_t)b * LQ * DD;
  const unsigned short* Vbase = Vs + (size_t)b * LQ * DD;

  // K frags (B-operand of swapped QK): data K[j=l15][d=g*8+r] per kh-half
  short8 ka[2][2];
#pragma unroll
  for (int jsl = 0; jsl < 2; ++jsl)
#pragma unroll
    for (int kh = 0; kh < 2; ++kh)
      ka[jsl][kh] = *(const short8*)(Kb + ((size_t)b * LQ + j0 + jsl * 16 + l15) * DD + kh * 32 + g * 8);

  f32x4 acc[2][4];
#pragma unroll
  for (int jsl = 0; jsl < 2; ++jsl)
#pragma unroll
    for (int ds = 0; ds < 4; ++ds) acc[jsl][ds] = (f32x4){0.f, 0.f, 0.f, 0.f};

  const int ibase = p * 512;
  // staging source addressing (row-coalesced 1KB blocks)
  const int qrow = lane >> 3;                 // + 8*kk
  const int qcol = ((lane & 7) ^ (lane >> 3)) << 3;
  // V [ds][g][r][c] subtile layout: i = vgr, d = kk*32 + vdc
  const int vgr = ((lane & 31) >> 3) * 4 + ((lane >> 1) & 3);
  const int vdc = (lane >> 5) * 16 + (lane & 1) * 8;

  const unsigned sbyte = (unsigned)(size_t)&stage[w][0][0];

#define STAGE(BUF, I0) do { \
    _Pragma("unroll") \
    for (int kk = 0; kk < 2; ++kk) { \
      gl_lds16(Qbase + (size_t)((I0) + kk * 8 + qrow) * DD + qcol, &stage[w][BUF][kk * 512]); \
      gl_lds16(Vbase + (size_t)((I0) + vgr) * DD + kk * 32 + vdc, &stage[w][BUF][1024 + kk * 512]); \
    } \
  } while (0)

  STAGE(0, ibase);
  STAGE(1, ibase + 16);

  for (int itr = 0; itr < 32; ++itr) {
    const int cur = itr & 1;
    // tile itr (issued 2 iters ago) retired; next tile's 4 loads may fly
    if (itr < 31) asm volatile("s_waitcnt vmcnt(4)" ::: "memory");
    else          asm volatile("s_waitcnt vmcnt(0)" ::: "memory");

    // Q A-frags from swizzled LDS: data Q[i=l15][d=kh*32+g*8+r]
    short8 qf[2];
#pragma unroll
    for (int kh = 0; kh < 2; ++kh)
      qf[kh] = *(const short8*)(&stage[w][cur][l15 * 64 + (((kh * 4 + g) ^ (l15 & 7)) << 3)]);

    // V K=16 B-frags via tr-read (frag ds at +ds*512); ends lgkmcnt(0) =>
    // Q reads also landed in regs before the buffer is re-staged below.
    unsigned long long v0, v1, v2, v3;
    const unsigned av = sbyte + cur * 4096 + 2048 + g * 128 + l15 * 8;
    asm volatile(
        "ds_read_b64_tr_b16 %0, %4\n\t"
        "ds_read_b64_tr_b16 %1, %4 offset:512\n\t"
        "ds_read_b64_tr_b16 %2, %4 offset:1024\n\t"
        "ds_read_b64_tr_b16 %3, %4 offset:1536\n\t"
        "s_waitcnt lgkmcnt(0)"
        : "=&v"(v0), "=&v"(v1), "=&v"(v2), "=&v"(v3)
        : "v"(av) : "memory");
    short4v vf[4];
    vf[0] = __builtin_bit_cast(short4v, v0);
    vf[1] = __builtin_bit_cast(short4v, v1);
    vf[2] = __builtin_bit_cast(short4v, v2);
    vf[3] = __builtin_bit_cast(short4v, v3);

    // re-stage this buffer with tile itr+2 (reads above already in regs)
    if (itr + 2 < 32) STAGE(cur, ibase + (itr + 2) * 16);

    // per j-subtile: swapped QK -> P (j lane-local) -> pack -> K=16 PV
    __builtin_amdgcn_s_setprio(1);
#pragma unroll
    for (int jsl = 0; jsl < 2; ++jsl) {
      f32x4 tt = __builtin_amdgcn_mfma_f32_16x16x32_bf16(
          qf[0], ka[jsl][0], (f32x4){0.f, 0.f, 0.f, 0.f}, 0, 0, 0);
      tt = __builtin_amdgcn_mfma_f32_16x16x32_bf16(qf[1], ka[jsl][1], tt, 0, 0, 0);
      const unsigned a0 = __builtin_bit_cast(unsigned, ex2(tt[0] * C1)) + 0x8000u;
      const unsigned a1 = __builtin_bit_cast(unsigned, ex2(tt[1] * C1)) + 0x8000u;
      const unsigned a2 = __builtin_bit_cast(unsigned, ex2(tt[2] * C1)) + 0x8000u;
      const unsigned a3 = __builtin_bit_cast(unsigned, ex2(tt[3] * C1)) + 0x8000u;
      uint2v uu;
      uu[0] = __builtin_amdgcn_perm(a1, a0, 0x07060302u);
      uu[1] = __builtin_amdgcn_perm(a3, a2, 0x07060302u);
      const short4v pa = __builtin_bit_cast(short4v, uu);
      acc[jsl][0] = mfma16(pa, vf[0], acc[jsl][0]);
      acc[jsl][1] = mfma16(pa, vf[1], acc[jsl][1]);
      acc[jsl][2] = mfma16(pa, vf[2], acc[jsl][2]);
      acc[jsl][3] = mfma16(pa, vf[3], acc[jsl][3]);
    }
    __builtin_amdgcn_s_setprio(0);
  }
#undef STAGE

  // cross-wave i-reduce: all 16 waves dump acc (128 KB = stage reuse),
  // wave w sums + stores j-rows [w*4, w*4+4) over the 8 i-range copies.
  __syncthreads();
  float* red = (float*)&stage[0][0][0];   // 16 x 2048 floats = 128 KB
#pragma unroll
  for (int jsl = 0; jsl < 2; ++jsl)
#pragma unroll
    for (int ds = 0; ds < 4; ++ds)
#pragma unroll
      for (int qq = 0; qq < 4; ++qq)
        red[w * 2048 + (jsl * 16 + g * 4 + qq) * 64 + ds * 16 + l15] = acc[jsl][ds][qq];
  __syncthreads();
  {
    float* op = out + ((size_t)b * LQ + jt * 64) * DD;
#pragma unroll
    for (int rr = 0; rr < 4; ++rr) {
      const int r = w * 4 + rr;          // 0..63 within the j-tile
      const int sr = r >> 5, rl = r & 31;
      float s = 0.f;
#pragma unroll
      for (int pp = 0; pp < 8; ++pp)
        s += red[(pp * 2 + sr) * 2048 + rl * 64 + lane];
      op[r * 64 + lane] = s;
    }
  }
}

// ---------------------------------------------------------------------------
extern "C" void kernel_launch(void* const* d_in, const int* in_sizes, int n_in,
                              void* d_out, int out_size, void* d_ws, size_t ws_size,
                              hipStream_t stream) {
  const float* q = (const float*)d_in[0];
  const float* k = (const float*)d_in[1];
  const float* v = (const float*)d_in[2];

  unsigned short* Qb = (unsigned short*)d_ws;
  unsigned short* Kb = Qb + NTOT;
  unsigned short* Vb = Kb + NTOT;
  unsigned short* Vs = Vb + NTOT;
  float* part_ls = (float*)(Vs + NTOT);
  float* outp = (float*)d_out;

  prep_kernel<<<1536, 256, 0, stream>>>(q, k, v, Qb, Kb, Vb);
  stats_kernel<<<NB * 16 * 8, 256, 0, stream>>>(Qb, Kb, part_ls);
  combine_kernel<<<512, 256, 0, stream>>>(part_ls, Vb, Vs);
  attn_out_kernel<<<NB * 64, 1024, 0, stream>>>(Qb, Kb, Vs, outp);
}

// Round 17
// 52.467 us; speedup vs baseline: 1.1606x; 1.1606x over previous
//
#include <hip/hip_runtime.h>
#include <hip/hip_bf16.h>

#define LQ 4096
#define DD 64
#define NB 4
#define NTOT ((size_t)NB * LQ * DD)
#define NROW ((size_t)NB * LQ)
#define NJC 16

typedef __attribute__((ext_vector_type(4))) float f32x4;
typedef __attribute__((ext_vector_type(8))) short short8;
typedef __attribute__((ext_vector_type(4))) short short4v;
typedef __attribute__((ext_vector_type(2))) unsigned int uint2v;
typedef __attribute__((ext_vector_type(4))) unsigned short ushort4v;

static __device__ __forceinline__ unsigned short f2bf(float x) {
  __hip_bfloat16 h = __float2bfloat16(x);
  return __builtin_bit_cast(unsigned short, h);
}
static __device__ __forceinline__ float ex2(float x) { return __builtin_amdgcn_exp2f(x); }

static __device__ __forceinline__ f32x4 mfma16(short4v a, short4v b, f32x4 c) {
#if __has_builtin(__builtin_amdgcn_mfma_f32_16x16x16bf16_1k)
  return __builtin_amdgcn_mfma_f32_16x16x16bf16_1k(a, b, c, 0, 0, 0);
#else
  asm volatile("v_mfma_f32_16x16x16_bf16 %0, %1, %2, %0"
               : "+v"(c) : "v"(a), "v"(b));
  return c;
#endif
}

// score scale folded into log2 domain: s2 = T * (0.125 * log2(e))
#define C1 0.18033688011112042f

// ---------------------------------------------------------------------------
// Fragment-packed layouts (bf16, per batch, tile = 16 rows):
//   Qf/Kf: word (T, kh, lane): X[T*16 + (lane&15)][kh*32 + (lane>>4)*8 + c]
//          at  ((T*2+kh)*64 + lane)*8 + c ,  c = 0..7
//   Vf:    word (T, dp, lane): low c=0..3 -> frag ds=2dp, high -> ds=2dp+1:
//          V[T*16 + (lane>>4)*4 + (c&3)][(2dp+(c>>2))*16 + (lane&15)]
// Every MFMA fragment load = one coalesced global_load_dwordx4.
// ---------------------------------------------------------------------------

// ---------------------------------------------------------------------------
// prep: Q,K fp32 -> fragment-packed bf16 Qf, Kf (LDS-transpose per 64-row slab)
// grid: NB*64 blocks of 256
// ---------------------------------------------------------------------------
__global__ __launch_bounds__(256) void prep_kernel(
    const float* __restrict__ q, const float* __restrict__ k,
    unsigned short* __restrict__ Qf, unsigned short* __restrict__ Kf)
{
  __shared__ __align__(16) unsigned short tile[64][72];
  const int bx = blockIdx.x;
  const int b = bx >> 6, s = bx & 63;
  const int tid = threadIdx.x;
  const int r = tid >> 2, c0 = (tid & 3) << 4;
  const int w = tid >> 6, lane = tid & 63;
  const int l15 = lane & 15, g = lane >> 4;
  const size_t rowbase = ((size_t)b * LQ + s * 64 + r) * DD + c0;
  const size_t bbase = (size_t)b * LQ * DD;

#pragma unroll
  for (int arr = 0; arr < 2; ++arr) {
    const float* src = arr ? k : q;
    unsigned short* dst = arr ? Kf : Qf;
    ushort4v o[4];
#pragma unroll
    for (int e = 0; e < 4; ++e) {
      const f32x4 x = *(const f32x4*)(src + rowbase + e * 4);
      o[e] = (ushort4v){ f2bf(x[0]), f2bf(x[1]), f2bf(x[2]), f2bf(x[3]) };
    }
    if (arr) __syncthreads();   // phase-2 reads of prev array done
#pragma unroll
    for (int e = 0; e < 4; ++e) *(ushort4v*)(&tile[r][c0 + e * 4]) = o[e];
    __syncthreads();
    const int T = s * 4 + w;
#pragma unroll
    for (int kh = 0; kh < 2; ++kh) {
      const unsigned short* pp = &tile[w * 16 + l15][kh * 32 + g * 8];
      const ushort4v lo = *(const ushort4v*)pp;
      const ushort4v hi = *(const ushort4v*)(pp + 4);
      unsigned short* od = dst + bbase + (((size_t)T * 2 + kh) * 64 + lane) * 8;
      *(ushort4v*)od = lo;
      *(ushort4v*)(od + 4) = hi;
    }
  }
}

// ---------------------------------------------------------------------------
// stats: part_ls[jc][b*LQ+i] = sum_{j in chunk jc} exp2(T[i,j]*C1)
// grid: 1024 blocks of 256 (XCD-partitioned), 4 blocks/CU, LDS-free,
// no barriers. Wave owns 64 i (4 resident Q A-frag tiles); walks 16 K j-tiles
// with triple-buffered register frags (compiler-counted vmcnt).
// ---------------------------------------------------------------------------
__global__ __launch_bounds__(256) void stats_kernel(
    const unsigned short* __restrict__ Qf, const unsigned short* __restrict__ Kf,
    float* __restrict__ part_ls)
{
  const int bx = blockIdx.x;
  const int x = bx & 7, kk = bx >> 3;
  const int b = x >> 1;
  const int jc = ((x & 1) << 3) + (kk >> 4);
  const int it = kk & 15;
  const int tid = threadIdx.x, w = tid >> 6, lane = tid & 63;
  const int l15 = lane & 15, g = lane >> 4;
  const size_t bbase = (size_t)b * LQ * DD;
  const unsigned short* Qp = Qf + bbase;
  const unsigned short* Kp = Kf + bbase;

  short8 aq[4][2];
#pragma unroll
  for (int is = 0; is < 4; ++is)
#pragma unroll
    for (int kh = 0; kh < 2; ++kh) {
      const int T = it * 16 + w * 4 + is;
      aq[is][kh] = *(const short8*)(Qp + (((size_t)T * 2 + kh) * 64 + lane) * 8);
    }

  float ls[4][4];
#pragma unroll
  for (int is = 0; is < 4; ++is)
#pragma unroll
    for (int qq = 0; qq < 4; ++qq) ls[is][qq] = 0.f;

  const int J0 = jc * 16;
  short8 kf[3][2];
#pragma unroll
  for (int pb = 0; pb < 2; ++pb)
#pragma unroll
    for (int kh = 0; kh < 2; ++kh)
      kf[pb][kh] = *(const short8*)(Kp + (((size_t)(J0 + pb) * 2 + kh) * 64 + lane) * 8);

#pragma unroll
  for (int itr = 0; itr < 16; ++itr) {
    const int buf = itr % 3;
    if (itr + 2 < 16) {
      const int nb2 = (itr + 2) % 3;
#pragma unroll
      for (int kh = 0; kh < 2; ++kh)
        kf[nb2][kh] = *(const short8*)(Kp + (((size_t)(J0 + itr + 2) * 2 + kh) * 64 + lane) * 8);
    }
#pragma unroll
    for (int is = 0; is < 4; ++is) {
      f32x4 tt = __builtin_amdgcn_mfma_f32_16x16x32_bf16(
          aq[is][0], kf[buf][0], (f32x4){0.f, 0.f, 0.f, 0.f}, 0, 0, 0);
      tt = __builtin_amdgcn_mfma_f32_16x16x32_bf16(aq[is][1], kf[buf][1], tt, 0, 0, 0);
#pragma unroll
      for (int qq = 0; qq < 4; ++qq) ls[is][qq] += ex2(tt[qq] * C1);
    }
  }
  // sum over the 16 j-lanes (xor 1,2,4,8 stays in 16-lane group)
#pragma unroll
  for (int mask = 1; mask <= 8; mask <<= 1)
#pragma unroll
    for (int is = 0; is < 4; ++is)
#pragma unroll
      for (int qq = 0; qq < 4; ++qq) ls[is][qq] += __shfl_xor(ls[is][qq], mask, 64);
  if (l15 == 0) {
#pragma unroll
    for (int is = 0; is < 4; ++is) {
      const int T = it * 16 + w * 4 + is;
#pragma unroll
      for (int qq = 0; qq < 4; ++qq)
        part_ls[(size_t)jc * NROW + b * LQ + T * 16 + g * 4 + qq] = ls[is][qq];
    }
  }
}

// ---------------------------------------------------------------------------
// combine: Vf = fragment-packed bf16 of V/l ,  l_r = sum_{jc} part_ls[jc][r]
// grid: NB*64 blocks of 256 (LDS-transpose per 64-row slab)
// ---------------------------------------------------------------------------
__global__ __launch_bounds__(256) void combine_kernel(
    const float* __restrict__ part_ls, const float* __restrict__ v,
    unsigned short* __restrict__ Vf)
{
  __shared__ __align__(16) unsigned short tile[64][72];
  const int bx = blockIdx.x;
  const int b = bx >> 6, s = bx & 63;
  const int tid = threadIdx.x;
  const int r = tid >> 2, c0 = (tid & 3) << 4;
  const int w = tid >> 6, lane = tid & 63;
  const int l15 = lane & 15, g = lane >> 4;
  const int row = b * LQ + s * 64 + r;

  float l = 0.f;
#pragma unroll
  for (int jc = 0; jc < NJC; ++jc) l += part_ls[(size_t)jc * NROW + row];
  const float sc = 1.0f / l;

  const size_t rowbase = (size_t)row * DD + c0;
#pragma unroll
  for (int e = 0; e < 4; ++e) {
    const f32x4 xv = *(const f32x4*)(v + rowbase + e * 4);
    ushort4v o = { f2bf(xv[0] * sc), f2bf(xv[1] * sc),
                   f2bf(xv[2] * sc), f2bf(xv[3] * sc) };
    *(ushort4v*)(&tile[r][c0 + e * 4]) = o;
  }
  __syncthreads();
  const int T = s * 4 + w;
  const size_t bbase = (size_t)b * LQ * DD;
#pragma unroll
  for (int dp = 0; dp < 2; ++dp) {
    ushort4v lo, hi;
#pragma unroll
    for (int c = 0; c < 4; ++c) {
      lo[c] = tile[w * 16 + g * 4 + c][(2 * dp) * 16 + l15];
      hi[c] = tile[w * 16 + g * 4 + c][(2 * dp + 1) * 16 + l15];
    }
    unsigned short* od = Vf + bbase + (((size_t)T * 2 + dp) * 64 + lane) * 8;
    *(ushort4v*)od = lo;
    *(ushort4v*)(od + 4) = hi;
  }
}

// ---------------------------------------------------------------------------
// attn_out: out[j][d] = sum_i exp2(T[j,i]*C1) * Vnorm[i][d]   (fp32)
// grid: 256 blocks (XCD-partitioned: batch pinned to XCD pair) of 1024
// (16 waves = 4 waves/SIMD). Wave (p=w>>1, sub=w&1): j-half jt*64+sub*32,
// i-tiles [p*32, +32). MAIN LOOP IS LDS-FREE: all fragments arrive as
// coalesced dwordx4 loads from the packed layouts, triple-buffered in
// registers (compiler-counted vmcnt, no barriers, no lgkmcnt walls).
// Swapped QK keeps P lane-local; PV via K=16 MFMAs (r14-verified math).
// ---------------------------------------------------------------------------
__global__ __launch_bounds__(1024) void attn_out_kernel(
    const unsigned short* __restrict__ Qf, const unsigned short* __restrict__ Kf,
    const unsigned short* __restrict__ Vf, float* __restrict__ out)
{
  __shared__ float red[16 * 2048];   // 128 KB, epilogue only

  const int bx = blockIdx.x;
  const int x = bx & 7;
  const int b = x >> 1;
  const int jt = ((x & 1) << 5) + (bx >> 3);
  const int tid = threadIdx.x, w = tid >> 6, lane = tid & 63;
  const int p = w >> 1, sub = w & 1;
  const int l15 = lane & 15, g = lane >> 4;

  const size_t bbase = (size_t)b * LQ * DD;
  const unsigned short* Qp = Qf + bbase;
  const unsigned short* Kp = Kf + bbase;
  const unsigned short* Vp = Vf + bbase;

  // K frags (B-operand of swapped QK), resident
  short8 ka[2][2];
#pragma unroll
  for (int jsl = 0; jsl < 2; ++jsl)
#pragma unroll
    for (int kh = 0; kh < 2; ++kh) {
      const int JT = jt * 4 + sub * 2 + jsl;
      ka[jsl][kh] = *(const short8*)(Kp + (((size_t)JT * 2 + kh) * 64 + lane) * 8);
    }

  f32x4 acc[2][4];
#pragma unroll
  for (int jsl = 0; jsl < 2; ++jsl)
#pragma unroll
    for (int ds = 0; ds < 4; ++ds) acc[jsl][ds] = (f32x4){0.f, 0.f, 0.f, 0.f};

  const int T0 = p * 32;
  short8 qb[3][2], vb[3][2];
#pragma unroll
  for (int pb = 0; pb < 2; ++pb) {
#pragma unroll
    for (int kh = 0; kh < 2; ++kh)
      qb[pb][kh] = *(const short8*)(Qp + (((size_t)(T0 + pb) * 2 + kh) * 64 + lane) * 8);
#pragma unroll
    for (int dp = 0; dp < 2; ++dp)
      vb[pb][dp] = *(const short8*)(Vp + (((size_t)(T0 + pb) * 2 + dp) * 64 + lane) * 8);
  }

#pragma unroll
  for (int itr = 0; itr < 32; ++itr) {
    const int buf = itr % 3;
    if (itr + 2 < 32) {
      const int nb2 = (itr + 2) % 3;
      const int Tn = T0 + itr + 2;
#pragma unroll
      for (int kh = 0; kh < 2; ++kh)
        qb[nb2][kh] = *(const short8*)(Qp + (((size_t)Tn * 2 + kh) * 64 + lane) * 8);
#pragma unroll
      for (int dp = 0; dp < 2; ++dp)
        vb[nb2][dp] = *(const short8*)(Vp + (((size_t)Tn * 2 + dp) * 64 + lane) * 8);
    }

    union VU { short8 s8; short4v s4[2]; } vu0, vu1;
    vu0.s8 = vb[buf][0];
    vu1.s8 = vb[buf][1];

    __builtin_amdgcn_s_setprio(1);
#pragma unroll
    for (int jsl = 0; jsl < 2; ++jsl) {
      f32x4 tt = __builtin_amdgcn_mfma_f32_16x16x32_bf16(
          qb[buf][0], ka[jsl][0], (f32x4){0.f, 0.f, 0.f, 0.f}, 0, 0, 0);
      tt = __builtin_amdgcn_mfma_f32_16x16x32_bf16(qb[buf][1], ka[jsl][1], tt, 0, 0, 0);
      const unsigned a0 = __builtin_bit_cast(unsigned, ex2(tt[0] * C1)) + 0x8000u;
      const unsigned a1 = __builtin_bit_cast(unsigned, ex2(tt[1] * C1)) + 0x8000u;
      const unsigned a2 = __builtin_bit_cast(unsigned, ex2(tt[2] * C1)) + 0x8000u;
      const unsigned a3 = __builtin_bit_cast(unsigned, ex2(tt[3] * C1)) + 0x8000u;
      uint2v uu;
      uu[0] = __builtin_amdgcn_perm(a1, a0, 0x07060302u);
      uu[1] = __builtin_amdgcn_perm(a3, a2, 0x07060302u);
      const short4v pa = __builtin_bit_cast(short4v, uu);
      acc[jsl][0] = mfma16(pa, vu0.s4[0], acc[jsl][0]);
      acc[jsl][1] = mfma16(pa, vu0.s4[1], acc[jsl][1]);
      acc[jsl][2] = mfma16(pa, vu1.s4[0], acc[jsl][2]);
      acc[jsl][3] = mfma16(pa, vu1.s4[1], acc[jsl][3]);
    }
    __builtin_amdgcn_s_setprio(0);
  }

  // cross-wave i-reduce (r16-verified): dump acc, wave w sums j-rows
  // [w*4, w*4+4) over the 8 i-range copies of its sub-half.
  __syncthreads();
#pragma unroll
  for (int jsl = 0; jsl < 2; ++jsl)
#pragma unroll
    for (int ds = 0; ds < 4; ++ds)
#pragma unroll
      for (int qq = 0; qq < 4; ++qq)
        red[w * 2048 + (jsl * 16 + g * 4 + qq) * 64 + ds * 16 + l15] = acc[jsl][ds][qq];
  __syncthreads();
  {
    float* op = out + ((size_t)b * LQ + jt * 64) * DD;
#pragma unroll
    for (int rr = 0; rr < 4; ++rr) {
      const int r = w * 4 + rr;          // 0..63 within the j-tile
      const int sr = r >> 5, rl = r & 31;
      float s = 0.f;
#pragma unroll
      for (int pp = 0; pp < 8; ++pp)
        s += red[(pp * 2 + sr) * 2048 + rl * 64 + lane];
      op[r * 64 + lane] = s;
    }
  }
}

// ---------------------------------------------------------------------------
extern "C" void kernel_launch(void* const* d_in, const int* in_sizes, int n_in,
                              void* d_out, int out_size, void* d_ws, size_t ws_size,
                              hipStream_t stream) {
  const float* q = (const float*)d_in[0];
  const float* k = (const float*)d_in[1];
  const float* v = (const float*)d_in[2];

  unsigned short* Qf = (unsigned short*)d_ws;
  unsigned short* Kf = Qf + NTOT;
  unsigned short* Vf = Kf + NTOT;
  float* part_ls = (float*)(Vf + NTOT);
  float* outp = (float*)d_out;

  prep_kernel<<<NB * 64, 256, 0, stream>>>(q, k, Qf, Kf);
  stats_kernel<<<1024, 256, 0, stream>>>(Qf, Kf, part_ls);
  combine_kernel<<<NB * 64, 256, 0, stream>>>(part_ls, v, Vf);
  attn_out_kernel<<<256, 1024, 0, stream>>>(Qf, Kf, Vf, outp);
}

// Round 18
// 51.566 us; speedup vs baseline: 1.1809x; 1.0175x over previous
//
#include <hip/hip_runtime.h>
#include <hip/hip_bf16.h>

#define LQ 4096
#define DD 64
#define NB 4
#define NTOT ((size_t)NB * LQ * DD)
#define NROW ((size_t)NB * LQ)
#define NJC 16

typedef __attribute__((ext_vector_type(4))) float f32x4;
typedef __attribute__((ext_vector_type(8))) short short8;
typedef __attribute__((ext_vector_type(4))) short short4v;
typedef __attribute__((ext_vector_type(2))) unsigned int uint2v;
typedef __attribute__((ext_vector_type(4))) unsigned short ushort4v;

static __device__ __forceinline__ unsigned short f2bf(float x) {
  __hip_bfloat16 h = __float2bfloat16(x);
  return __builtin_bit_cast(unsigned short, h);
}
static __device__ __forceinline__ float ex2(float x) { return __builtin_amdgcn_exp2f(x); }

static __device__ __forceinline__ f32x4 mfma16(short4v a, short4v b, f32x4 c) {
#if __has_builtin(__builtin_amdgcn_mfma_f32_16x16x16bf16_1k)
  return __builtin_amdgcn_mfma_f32_16x16x16bf16_1k(a, b, c, 0, 0, 0);
#else
  asm volatile("v_mfma_f32_16x16x16_bf16 %0, %1, %2, %0"
               : "+v"(c) : "v"(a), "v"(b));
  return c;
#endif
}

// score scale folded into log2 domain: s2 = T * (0.125 * log2(e))
#define C1 0.18033688011112042f

// ---------------------------------------------------------------------------
// Fragment-packed layouts (bf16, per batch, tile = 16 rows):
//   Qf/Kf: word (T, kh, lane): X[T*16 + (lane&15)][kh*32 + (lane>>4)*8 + c]
//   Vf:    word (T, dp, lane): low c=0..3 -> frag ds=2dp, high -> ds=2dp+1:
//          V[T*16 + (lane>>4)*4 + (c&3)][(2dp+(c>>2))*16 + (lane&15)]
// Every MFMA fragment load = one coalesced global_load_dwordx4.
// ---------------------------------------------------------------------------

// ---------------------------------------------------------------------------
// prep: Q,K fp32 -> fragment-packed bf16 Qf, Kf (LDS-transpose per 64-row slab)
// ---------------------------------------------------------------------------
__global__ __launch_bounds__(256) void prep_kernel(
    const float* __restrict__ q, const float* __restrict__ k,
    unsigned short* __restrict__ Qf, unsigned short* __restrict__ Kf)
{
  __shared__ __align__(16) unsigned short tile[64][72];
  const int bx = blockIdx.x;
  const int b = bx >> 6, s = bx & 63;
  const int tid = threadIdx.x;
  const int r = tid >> 2, c0 = (tid & 3) << 4;
  const int w = tid >> 6, lane = tid & 63;
  const int l15 = lane & 15, g = lane >> 4;
  const size_t rowbase = ((size_t)b * LQ + s * 64 + r) * DD + c0;
  const size_t bbase = (size_t)b * LQ * DD;

#pragma unroll
  for (int arr = 0; arr < 2; ++arr) {
    const float* src = arr ? k : q;
    unsigned short* dst = arr ? Kf : Qf;
    ushort4v o[4];
#pragma unroll
    for (int e = 0; e < 4; ++e) {
      const f32x4 x = *(const f32x4*)(src + rowbase + e * 4);
      o[e] = (ushort4v){ f2bf(x[0]), f2bf(x[1]), f2bf(x[2]), f2bf(x[3]) };
    }
    if (arr) __syncthreads();   // phase-2 reads of prev array done
#pragma unroll
    for (int e = 0; e < 4; ++e) *(ushort4v*)(&tile[r][c0 + e * 4]) = o[e];
    __syncthreads();
    const int T = s * 4 + w;
#pragma unroll
    for (int kh = 0; kh < 2; ++kh) {
      const unsigned short* pp = &tile[w * 16 + l15][kh * 32 + g * 8];
      const ushort4v lo = *(const ushort4v*)pp;
      const ushort4v hi = *(const ushort4v*)(pp + 4);
      unsigned short* od = dst + bbase + (((size_t)T * 2 + kh) * 64 + lane) * 8;
      *(ushort4v*)od = lo;
      *(ushort4v*)(od + 4) = hi;
    }
  }
}

// ---------------------------------------------------------------------------
// stats: part_ls[jc][b*LQ+i] = sum_{j in chunk jc} exp2(T[i,j]*C1)
// grid: 1024 blocks of 256 (XCD-partitioned), LDS-free, no barriers.
// ---------------------------------------------------------------------------
__global__ __launch_bounds__(256) void stats_kernel(
    const unsigned short* __restrict__ Qf, const unsigned short* __restrict__ Kf,
    float* __restrict__ part_ls)
{
  const int bx = blockIdx.x;
  const int x = bx & 7, kk = bx >> 3;
  const int b = x >> 1;
  const int jc = ((x & 1) << 3) + (kk >> 4);
  const int it = kk & 15;
  const int tid = threadIdx.x, w = tid >> 6, lane = tid & 63;
  const int l15 = lane & 15, g = lane >> 4;
  const size_t bbase = (size_t)b * LQ * DD;
  const unsigned short* Qp = Qf + bbase;
  const unsigned short* Kp = Kf + bbase;

  short8 aq[4][2];
#pragma unroll
  for (int is = 0; is < 4; ++is)
#pragma unroll
    for (int kh = 0; kh < 2; ++kh) {
      const int T = it * 16 + w * 4 + is;
      aq[is][kh] = *(const short8*)(Qp + (((size_t)T * 2 + kh) * 64 + lane) * 8);
    }

  float ls[4][4];
#pragma unroll
  for (int is = 0; is < 4; ++is)
#pragma unroll
    for (int qq = 0; qq < 4; ++qq) ls[is][qq] = 0.f;

  const int J0 = jc * 16;
  short8 kf[3][2];
#pragma unroll
  for (int pb = 0; pb < 2; ++pb)
#pragma unroll
    for (int kh = 0; kh < 2; ++kh)
      kf[pb][kh] = *(const short8*)(Kp + (((size_t)(J0 + pb) * 2 + kh) * 64 + lane) * 8);

#pragma unroll
  for (int itr = 0; itr < 16; ++itr) {
    const int buf = itr % 3;
    if (itr + 2 < 16) {
      const int nb2 = (itr + 2) % 3;
#pragma unroll
      for (int kh = 0; kh < 2; ++kh)
        kf[nb2][kh] = *(const short8*)(Kp + (((size_t)(J0 + itr + 2) * 2 + kh) * 64 + lane) * 8);
    }
#pragma unroll
    for (int is = 0; is < 4; ++is) {
      f32x4 tt = __builtin_amdgcn_mfma_f32_16x16x32_bf16(
          aq[is][0], kf[buf][0], (f32x4){0.f, 0.f, 0.f, 0.f}, 0, 0, 0);
      tt = __builtin_amdgcn_mfma_f32_16x16x32_bf16(aq[is][1], kf[buf][1], tt, 0, 0, 0);
#pragma unroll
      for (int qq = 0; qq < 4; ++qq) ls[is][qq] += ex2(tt[qq] * C1);
    }
  }
#pragma unroll
  for (int mask = 1; mask <= 8; mask <<= 1)
#pragma unroll
    for (int is = 0; is < 4; ++is)
#pragma unroll
      for (int qq = 0; qq < 4; ++qq) ls[is][qq] += __shfl_xor(ls[is][qq], mask, 64);
  if (l15 == 0) {
#pragma unroll
    for (int is = 0; is < 4; ++is) {
      const int T = it * 16 + w * 4 + is;
#pragma unroll
      for (int qq = 0; qq < 4; ++qq)
        part_ls[(size_t)jc * NROW + b * LQ + T * 16 + g * 4 + qq] = ls[is][qq];
    }
  }
}

// ---------------------------------------------------------------------------
// combine: Vf = fragment-packed bf16 of V/l ,  l_r = sum_{jc} part_ls[jc][r]
// ---------------------------------------------------------------------------
__global__ __launch_bounds__(256) void combine_kernel(
    const float* __restrict__ part_ls, const float* __restrict__ v,
    unsigned short* __restrict__ Vf)
{
  __shared__ __align__(16) unsigned short tile[64][72];
  const int bx = blockIdx.x;
  const int b = bx >> 6, s = bx & 63;
  const int tid = threadIdx.x;
  const int r = tid >> 2, c0 = (tid & 3) << 4;
  const int w = tid >> 6, lane = tid & 63;
  const int l15 = lane & 15, g = lane >> 4;
  const int row = b * LQ + s * 64 + r;

  float l = 0.f;
#pragma unroll
  for (int jc = 0; jc < NJC; ++jc) l += part_ls[(size_t)jc * NROW + row];
  const float sc = 1.0f / l;

  const size_t rowbase = (size_t)row * DD + c0;
#pragma unroll
  for (int e = 0; e < 4; ++e) {
    const f32x4 xv = *(const f32x4*)(v + rowbase + e * 4);
    ushort4v o = { f2bf(xv[0] * sc), f2bf(xv[1] * sc),
                   f2bf(xv[2] * sc), f2bf(xv[3] * sc) };
    *(ushort4v*)(&tile[r][c0 + e * 4]) = o;
  }
  __syncthreads();
  const int T = s * 4 + w;
  const size_t bbase = (size_t)b * LQ * DD;
#pragma unroll
  for (int dp = 0; dp < 2; ++dp) {
    ushort4v lo, hi;
#pragma unroll
    for (int c = 0; c < 4; ++c) {
      lo[c] = tile[w * 16 + g * 4 + c][(2 * dp) * 16 + l15];
      hi[c] = tile[w * 16 + g * 4 + c][(2 * dp + 1) * 16 + l15];
    }
    unsigned short* od = Vf + bbase + (((size_t)T * 2 + dp) * 64 + lane) * 8;
    *(ushort4v*)od = lo;
    *(ushort4v*)(od + 4) = hi;
  }
}

// ---------------------------------------------------------------------------
// attn_out: out[j][d] = sum_i exp2(T[j,i]*C1) * Vnorm[i][d]   (fp32)
// grid: 256 blocks (XCD-pinned batches) of 512 (8 waves = 2 waves/SIMD).
// Wave w owns ALL 64 j of the block's j-tile (4 js, K resident) and walks
// i-tiles [w*32, +32) -- J_wave=64 halves Q/V L2 traffic vs r17. LDS-free
// main loop: fragments as coalesced dwordx4 loads, triple-buffered in
// registers (compiler-counted vmcnt). Swapped QK keeps P lane-local;
// PV via K=16 MFMAs. Cross-wave i-reduce via LDS at the end.
// ---------------------------------------------------------------------------
__global__ __launch_bounds__(512, 2) void attn_out_kernel(
    const unsigned short* __restrict__ Qf, const unsigned short* __restrict__ Kf,
    const unsigned short* __restrict__ Vf, float* __restrict__ out)
{
  __shared__ float red[8 * 4096];   // 128 KB, epilogue only

  const int bx = blockIdx.x;
  const int x = bx & 7;
  const int b = x >> 1;
  const int jt = ((x & 1) << 5) + (bx >> 3);   // 0..63
  const int tid = threadIdx.x, w = tid >> 6, lane = tid & 63;
  const int l15 = lane & 15, g = lane >> 4;

  const size_t bbase = (size_t)b * LQ * DD;
  const unsigned short* Qp = Qf + bbase;
  const unsigned short* Kp = Kf + bbase;
  const unsigned short* Vp = Vf + bbase;

  // K frags (B-operand of swapped QK), 4 js resident
  short8 ka[4][2];
#pragma unroll
  for (int js = 0; js < 4; ++js)
#pragma unroll
    for (int kh = 0; kh < 2; ++kh) {
      const int JT = jt * 4 + js;
      ka[js][kh] = *(const short8*)(Kp + (((size_t)JT * 2 + kh) * 64 + lane) * 8);
    }

  f32x4 acc[4][4];
#pragma unroll
  for (int js = 0; js < 4; ++js)
#pragma unroll
    for (int ds = 0; ds < 4; ++ds) acc[js][ds] = (f32x4){0.f, 0.f, 0.f, 0.f};

  const int T0 = w * 32;
  short8 qb[3][2], vb[3][2];
#pragma unroll
  for (int pb = 0; pb < 2; ++pb) {
#pragma unroll
    for (int kh = 0; kh < 2; ++kh)
      qb[pb][kh] = *(const short8*)(Qp + (((size_t)(T0 + pb) * 2 + kh) * 64 + lane) * 8);
#pragma unroll
    for (int dp = 0; dp < 2; ++dp)
      vb[pb][dp] = *(const short8*)(Vp + (((size_t)(T0 + pb) * 2 + dp) * 64 + lane) * 8);
  }

#pragma unroll
  for (int itr = 0; itr < 32; ++itr) {
    const int buf = itr % 3;
    if (itr + 2 < 32) {
      const int nb2 = (itr + 2) % 3;
      const int Tn = T0 + itr + 2;
#pragma unroll
      for (int kh = 0; kh < 2; ++kh)
        qb[nb2][kh] = *(const short8*)(Qp + (((size_t)Tn * 2 + kh) * 64 + lane) * 8);
#pragma unroll
      for (int dp = 0; dp < 2; ++dp)
        vb[nb2][dp] = *(const short8*)(Vp + (((size_t)Tn * 2 + dp) * 64 + lane) * 8);
    }

    union VU { short8 s8; short4v s4[2]; } vu0, vu1;
    vu0.s8 = vb[buf][0];
    vu1.s8 = vb[buf][1];

    __builtin_amdgcn_s_setprio(1);
#pragma unroll
    for (int js = 0; js < 4; ++js) {
      f32x4 tt = __builtin_amdgcn_mfma_f32_16x16x32_bf16(
          qb[buf][0], ka[js][0], (f32x4){0.f, 0.f, 0.f, 0.f}, 0, 0, 0);
      tt = __builtin_amdgcn_mfma_f32_16x16x32_bf16(qb[buf][1], ka[js][1], tt, 0, 0, 0);
      const unsigned a0 = __builtin_bit_cast(unsigned, ex2(tt[0] * C1)) + 0x8000u;
      const unsigned a1 = __builtin_bit_cast(unsigned, ex2(tt[1] * C1)) + 0x8000u;
      const unsigned a2 = __builtin_bit_cast(unsigned, ex2(tt[2] * C1)) + 0x8000u;
      const unsigned a3 = __builtin_bit_cast(unsigned, ex2(tt[3] * C1)) + 0x8000u;
      uint2v uu;
      uu[0] = __builtin_amdgcn_perm(a1, a0, 0x07060302u);
      uu[1] = __builtin_amdgcn_perm(a3, a2, 0x07060302u);
      const short4v pa = __builtin_bit_cast(short4v, uu);
      acc[js][0] = mfma16(pa, vu0.s4[0], acc[js][0]);
      acc[js][1] = mfma16(pa, vu0.s4[1], acc[js][1]);
      acc[js][2] = mfma16(pa, vu1.s4[0], acc[js][2]);
      acc[js][3] = mfma16(pa, vu1.s4[1], acc[js][3]);
    }
    __builtin_amdgcn_s_setprio(0);
  }

  // cross-wave i-reduce: 8 waves dump acc (128 KB), then 512 threads each
  // sum one (j, 8d) strip over the 8 i-range copies.
  __syncthreads();
#pragma unroll
  for (int js = 0; js < 4; ++js)
#pragma unroll
    for (int ds = 0; ds < 4; ++ds)
#pragma unroll
      for (int qq = 0; qq < 4; ++qq)
        red[w * 4096 + (js * 16 + g * 4 + qq) * 64 + ds * 16 + l15] = acc[js][ds][qq];
  __syncthreads();
  {
    float* op = out + ((size_t)b * LQ + jt * 64) * DD;
    const int jj = tid >> 3;            // 0..63
    const int d0 = (tid & 7) << 3;      // 0,8,..,56
    f32x4 s0 = (f32x4){0.f, 0.f, 0.f, 0.f};
    f32x4 s1 = (f32x4){0.f, 0.f, 0.f, 0.f};
#pragma unroll
    for (int u = 0; u < 8; ++u) {
      const f32x4 t0 = *(const f32x4*)&red[u * 4096 + jj * 64 + d0];
      const f32x4 t1 = *(const f32x4*)&red[u * 4096 + jj * 64 + d0 + 4];
      s0[0] += t0[0]; s0[1] += t0[1]; s0[2] += t0[2]; s0[3] += t0[3];
      s1[0] += t1[0]; s1[1] += t1[1]; s1[2] += t1[2]; s1[3] += t1[3];
    }
    *(f32x4*)(op + jj * 64 + d0) = s0;
    *(f32x4*)(op + jj * 64 + d0 + 4) = s1;
  }
}

// ---------------------------------------------------------------------------
extern "C" void kernel_launch(void* const* d_in, const int* in_sizes, int n_in,
                              void* d_out, int out_size, void* d_ws, size_t ws_size,
                              hipStream_t stream) {
  const float* q = (const float*)d_in[0];
  const float* k = (const float*)d_in[1];
  const float* v = (const float*)d_in[2];

  unsigned short* Qf = (unsigned short*)d_ws;
  unsigned short* Kf = Qf + NTOT;
  unsigned short* Vf = Kf + NTOT;
  float* part_ls = (float*)(Vf + NTOT);
  float* outp = (float*)d_out;

  prep_kernel<<<NB * 64, 256, 0, stream>>>(q, k, Qf, Kf);
  stats_kernel<<<1024, 256, 0, stream>>>(Qf, Kf, part_ls);
  combine_kernel<<<NB * 64, 256, 0, stream>>>(part_ls, v, Vf);
  attn_out_kernel<<<256, 512, 0, stream>>>(Qf, Kf, Vf, outp);
}

// Round 19
// 50.721 us; speedup vs baseline: 1.2006x; 1.0166x over previous
//
#include <hip/hip_runtime.h>
#include <hip/hip_bf16.h>

#define LQ 4096
#define DD 64
#define NB 4
#define NTOT ((size_t)NB * LQ * DD)
#define NROW ((size_t)NB * LQ)
#define NJC 16

typedef __attribute__((ext_vector_type(4))) float f32x4;
typedef __attribute__((ext_vector_type(8))) short short8;
typedef __attribute__((ext_vector_type(4))) short short4v;
typedef __attribute__((ext_vector_type(2))) unsigned int uint2v;
typedef __attribute__((ext_vector_type(4))) unsigned short ushort4v;

static __device__ __forceinline__ unsigned short f2bf(float x) {
  __hip_bfloat16 h = __float2bfloat16(x);
  return __builtin_bit_cast(unsigned short, h);
}
static __device__ __forceinline__ float ex2(float x) { return __builtin_amdgcn_exp2f(x); }

static __device__ __forceinline__ f32x4 mfma16(short4v a, short4v b, f32x4 c) {
#if __has_builtin(__builtin_amdgcn_mfma_f32_16x16x16bf16_1k)
  return __builtin_amdgcn_mfma_f32_16x16x16bf16_1k(a, b, c, 0, 0, 0);
#else
  asm volatile("v_mfma_f32_16x16x16_bf16 %0, %1, %2, %0"
               : "+v"(c) : "v"(a), "v"(b));
  return c;
#endif
}

// score scale folded into log2 domain: s2 = T * (0.125 * log2(e))
#define C1 0.18033688011112042f

// ---------------------------------------------------------------------------
// Fragment-packed layouts (bf16, per batch, tile = 16 rows):
//   Qf/Kf: word (T, kh, lane): X[T*16 + (lane&15)][kh*32 + (lane>>4)*8 + c]
//   Vf:    word (T, dp, lane): low c=0..3 -> frag ds=2dp, high -> ds=2dp+1:
//          V[T*16 + (lane>>4)*4 + (c&3)][(2dp+(c>>2))*16 + (lane&15)]
// Every MFMA fragment load = one coalesced global_load_dwordx4.
// ---------------------------------------------------------------------------

// ---------------------------------------------------------------------------
// prep: grid 512 of 256. bx<256: Q,K fp32 -> packed bf16 Qf,Kf.
//       bx>=256: V fp32 -> packed bf16 Vf (raw, no scale).
// ---------------------------------------------------------------------------
__global__ __launch_bounds__(256) void prep_kernel(
    const float* __restrict__ q, const float* __restrict__ k,
    const float* __restrict__ v,
    unsigned short* __restrict__ Qf, unsigned short* __restrict__ Kf,
    unsigned short* __restrict__ Vf)
{
  __shared__ __align__(16) unsigned short tile[64][72];
  const int bx = blockIdx.x;
  const int half = bx >> 8;
  const int b = (bx & 255) >> 6, s = bx & 63;
  const int tid = threadIdx.x;
  const int r = tid >> 2, c0 = (tid & 3) << 4;
  const int w = tid >> 6, lane = tid & 63;
  const int l15 = lane & 15, g = lane >> 4;
  const size_t rowbase = ((size_t)b * LQ + s * 64 + r) * DD + c0;
  const size_t bbase = (size_t)b * LQ * DD;
  const int T = s * 4 + w;

  if (half == 0) {
#pragma unroll
    for (int arr = 0; arr < 2; ++arr) {
      const float* src = arr ? k : q;
      unsigned short* dst = arr ? Kf : Qf;
      ushort4v o[4];
#pragma unroll
      for (int e = 0; e < 4; ++e) {
        const f32x4 x = *(const f32x4*)(src + rowbase + e * 4);
        o[e] = (ushort4v){ f2bf(x[0]), f2bf(x[1]), f2bf(x[2]), f2bf(x[3]) };
      }
      if (arr) __syncthreads();   // phase-2 reads of prev array done
#pragma unroll
      for (int e = 0; e < 4; ++e) *(ushort4v*)(&tile[r][c0 + e * 4]) = o[e];
      __syncthreads();
#pragma unroll
      for (int kh = 0; kh < 2; ++kh) {
        const unsigned short* pp = &tile[w * 16 + l15][kh * 32 + g * 8];
        const ushort4v lo = *(const ushort4v*)pp;
        const ushort4v hi = *(const ushort4v*)(pp + 4);
        unsigned short* od = dst + bbase + (((size_t)T * 2 + kh) * 64 + lane) * 8;
        *(ushort4v*)od = lo;
        *(ushort4v*)(od + 4) = hi;
      }
    }
  } else {
#pragma unroll
    for (int e = 0; e < 4; ++e) {
      const f32x4 xv = *(const f32x4*)(v + rowbase + e * 4);
      ushort4v o = { f2bf(xv[0]), f2bf(xv[1]), f2bf(xv[2]), f2bf(xv[3]) };
      *(ushort4v*)(&tile[r][c0 + e * 4]) = o;
    }
    __syncthreads();
#pragma unroll
    for (int dp = 0; dp < 2; ++dp) {
      ushort4v lo, hi;
#pragma unroll
      for (int c = 0; c < 4; ++c) {
        lo[c] = tile[w * 16 + g * 4 + c][(2 * dp) * 16 + l15];
        hi[c] = tile[w * 16 + g * 4 + c][(2 * dp + 1) * 16 + l15];
      }
      unsigned short* od = Vf + bbase + (((size_t)T * 2 + dp) * 64 + lane) * 8;
      *(ushort4v*)od = lo;
      *(ushort4v*)(od + 4) = hi;
    }
  }
}

// ---------------------------------------------------------------------------
// stats: part_ls[jc][b*LQ+i] = sum_{j in chunk jc} exp2(T[i,j]*C1)
// grid: 1024 blocks of 256 (XCD-partitioned), LDS-free, no barriers.
// ---------------------------------------------------------------------------
__global__ __launch_bounds__(256) void stats_kernel(
    const unsigned short* __restrict__ Qf, const unsigned short* __restrict__ Kf,
    float* __restrict__ part_ls)
{
  const int bx = blockIdx.x;
  const int x = bx & 7, kk = bx >> 3;
  const int b = x >> 1;
  const int jc = ((x & 1) << 3) + (kk >> 4);
  const int it = kk & 15;
  const int tid = threadIdx.x, w = tid >> 6, lane = tid & 63;
  const int l15 = lane & 15, g = lane >> 4;
  const size_t bbase = (size_t)b * LQ * DD;
  const unsigned short* Qp = Qf + bbase;
  const unsigned short* Kp = Kf + bbase;

  short8 aq[4][2];
#pragma unroll
  for (int is = 0; is < 4; ++is)
#pragma unroll
    for (int kh = 0; kh < 2; ++kh) {
      const int T = it * 16 + w * 4 + is;
      aq[is][kh] = *(const short8*)(Qp + (((size_t)T * 2 + kh) * 64 + lane) * 8);
    }

  float ls[4][4];
#pragma unroll
  for (int is = 0; is < 4; ++is)
#pragma unroll
    for (int qq = 0; qq < 4; ++qq) ls[is][qq] = 0.f;

  const int J0 = jc * 16;
  short8 kf[3][2];
#pragma unroll
  for (int pb = 0; pb < 2; ++pb)
#pragma unroll
    for (int kh = 0; kh < 2; ++kh)
      kf[pb][kh] = *(const short8*)(Kp + (((size_t)(J0 + pb) * 2 + kh) * 64 + lane) * 8);

#pragma unroll
  for (int itr = 0; itr < 16; ++itr) {
    const int buf = itr % 3;
    if (itr + 2 < 16) {
      const int nb2 = (itr + 2) % 3;
#pragma unroll
      for (int kh = 0; kh < 2; ++kh)
        kf[nb2][kh] = *(const short8*)(Kp + (((size_t)(J0 + itr + 2) * 2 + kh) * 64 + lane) * 8);
    }
#pragma unroll
    for (int is = 0; is < 4; ++is) {
      f32x4 tt = __builtin_amdgcn_mfma_f32_16x16x32_bf16(
          aq[is][0], kf[buf][0], (f32x4){0.f, 0.f, 0.f, 0.f}, 0, 0, 0);
      tt = __builtin_amdgcn_mfma_f32_16x16x32_bf16(aq[is][1], kf[buf][1], tt, 0, 0, 0);
#pragma unroll
      for (int qq = 0; qq < 4; ++qq) ls[is][qq] += ex2(tt[qq] * C1);
    }
  }
#pragma unroll
  for (int mask = 1; mask <= 8; mask <<= 1)
#pragma unroll
    for (int is = 0; is < 4; ++is)
#pragma unroll
      for (int qq = 0; qq < 4; ++qq) ls[is][qq] += __shfl_xor(ls[is][qq], mask, 64);
  if (l15 == 0) {
#pragma unroll
    for (int is = 0; is < 4; ++is) {
      const int T = it * 16 + w * 4 + is;
#pragma unroll
      for (int qq = 0; qq < 4; ++qq)
        part_ls[(size_t)jc * NROW + b * LQ + T * 16 + g * 4 + qq] = ls[is][qq];
    }
  }
}

// ---------------------------------------------------------------------------
// logify: c2[x] = log2( sum_{jc<16} part_ls[jc][x] )   (64 blocks of 256)
// ---------------------------------------------------------------------------
__global__ __launch_bounds__(256) void logify_kernel(
    const float* __restrict__ part_ls, float* __restrict__ c2)
{
  const int x = blockIdx.x * 256 + threadIdx.x;
  float s = 0.f;
#pragma unroll
  for (int jc = 0; jc < NJC; ++jc) s += part_ls[(size_t)jc * NROW + x];
  c2[x] = __builtin_amdgcn_logf(s);  // v_log_f32 = log2
}

// ---------------------------------------------------------------------------
// attn_out: out[j][d] = sum_i exp2(T[j,i]*C1 - c2[i]) * V[i][d]   (fp32)
// grid: 256 blocks (XCD-pinned batches) of 512 (8 waves). Wave w owns all
// 64 j of the block's j-tile (4 js, K resident) and walks i-tiles
// [w*32,+32). LDS-free main loop: fragments + per-tile c2 f32x4 as
// coalesced loads, triple-buffered in registers. Swapped QK keeps P
// lane-local; normalization folded into the exp via fma(tt, C1, -c2).
// PV via K=16 MFMAs. Cross-wave i-reduce via LDS at the end.
// ---------------------------------------------------------------------------
__global__ __launch_bounds__(512, 2) void attn_out_kernel(
    const unsigned short* __restrict__ Qf, const unsigned short* __restrict__ Kf,
    const unsigned short* __restrict__ Vf, const float* __restrict__ c2,
    float* __restrict__ out)
{
  __shared__ float red[8 * 4096];   // 128 KB, epilogue only

  const int bx = blockIdx.x;
  const int x = bx & 7;
  const int b = x >> 1;
  const int jt = ((x & 1) << 5) + (bx >> 3);   // 0..63
  const int tid = threadIdx.x, w = tid >> 6, lane = tid & 63;
  const int l15 = lane & 15, g = lane >> 4;

  const size_t bbase = (size_t)b * LQ * DD;
  const unsigned short* Qp = Qf + bbase;
  const unsigned short* Kp = Kf + bbase;
  const unsigned short* Vp = Vf + bbase;
  const float* c2p = c2 + b * LQ + g * 4;

  // K frags (B-operand of swapped QK), 4 js resident
  short8 ka[4][2];
#pragma unroll
  for (int js = 0; js < 4; ++js)
#pragma unroll
    for (int kh = 0; kh < 2; ++kh) {
      const int JT = jt * 4 + js;
      ka[js][kh] = *(const short8*)(Kp + (((size_t)JT * 2 + kh) * 64 + lane) * 8);
    }

  f32x4 acc[4][4];
#pragma unroll
  for (int js = 0; js < 4; ++js)
#pragma unroll
    for (int ds = 0; ds < 4; ++ds) acc[js][ds] = (f32x4){0.f, 0.f, 0.f, 0.f};

  const int T0 = w * 32;
  short8 qb[3][2], vb[3][2];
  f32x4 cb[3];
#pragma unroll
  for (int pb = 0; pb < 2; ++pb) {
#pragma unroll
    for (int kh = 0; kh < 2; ++kh)
      qb[pb][kh] = *(const short8*)(Qp + (((size_t)(T0 + pb) * 2 + kh) * 64 + lane) * 8);
#pragma unroll
    for (int dp = 0; dp < 2; ++dp)
      vb[pb][dp] = *(const short8*)(Vp + (((size_t)(T0 + pb) * 2 + dp) * 64 + lane) * 8);
    cb[pb] = *(const f32x4*)(c2p + (T0 + pb) * 16);
  }

#pragma unroll
  for (int itr = 0; itr < 32; ++itr) {
    const int buf = itr % 3;
    if (itr + 2 < 32) {
      const int nb2 = (itr + 2) % 3;
      const int Tn = T0 + itr + 2;
#pragma unroll
      for (int kh = 0; kh < 2; ++kh)
        qb[nb2][kh] = *(const short8*)(Qp + (((size_t)Tn * 2 + kh) * 64 + lane) * 8);
#pragma unroll
      for (int dp = 0; dp < 2; ++dp)
        vb[nb2][dp] = *(const short8*)(Vp + (((size_t)Tn * 2 + dp) * 64 + lane) * 8);
      cb[nb2] = *(const f32x4*)(c2p + Tn * 16);
    }

    union VU { short8 s8; short4v s4[2]; } vu0, vu1;
    vu0.s8 = vb[buf][0];
    vu1.s8 = vb[buf][1];
    const f32x4 cc = cb[buf];

    __builtin_amdgcn_s_setprio(1);
#pragma unroll
    for (int js = 0; js < 4; ++js) {
      f32x4 tt = __builtin_amdgcn_mfma_f32_16x16x32_bf16(
          qb[buf][0], ka[js][0], (f32x4){0.f, 0.f, 0.f, 0.f}, 0, 0, 0);
      tt = __builtin_amdgcn_mfma_f32_16x16x32_bf16(qb[buf][1], ka[js][1], tt, 0, 0, 0);
      const unsigned a0 = __builtin_bit_cast(unsigned, ex2(__builtin_fmaf(tt[0], C1, -cc[0]))) + 0x8000u;
      const unsigned a1 = __builtin_bit_cast(unsigned, ex2(__builtin_fmaf(tt[1], C1, -cc[1]))) + 0x8000u;
      const unsigned a2 = __builtin_bit_cast(unsigned, ex2(__builtin_fmaf(tt[2], C1, -cc[2]))) + 0x8000u;
      const unsigned a3 = __builtin_bit_cast(unsigned, ex2(__builtin_fmaf(tt[3], C1, -cc[3]))) + 0x8000u;
      uint2v uu;
      uu[0] = __builtin_amdgcn_perm(a1, a0, 0x07060302u);
      uu[1] = __builtin_amdgcn_perm(a3, a2, 0x07060302u);
      const short4v pa = __builtin_bit_cast(short4v, uu);
      acc[js][0] = mfma16(pa, vu0.s4[0], acc[js][0]);
      acc[js][1] = mfma16(pa, vu0.s4[1], acc[js][1]);
      acc[js][2] = mfma16(pa, vu1.s4[0], acc[js][2]);
      acc[js][3] = mfma16(pa, vu1.s4[1], acc[js][3]);
    }
    __builtin_amdgcn_s_setprio(0);
  }

  // cross-wave i-reduce: 8 waves dump acc (128 KB), then 512 threads each
  // sum one (j, 8d) strip over the 8 i-range copies.
  __syncthreads();
#pragma unroll
  for (int js = 0; js < 4; ++js)
#pragma unroll
    for (int ds = 0; ds < 4; ++ds)
#pragma unroll
      for (int qq = 0; qq < 4; ++qq)
        red[w * 4096 + (js * 16 + g * 4 + qq) * 64 + ds * 16 + l15] = acc[js][ds][qq];
  __syncthreads();
  {
    float* op = out + ((size_t)b * LQ + jt * 64) * DD;
    const int jj = tid >> 3;            // 0..63
    const int d0 = (tid & 7) << 3;      // 0,8,..,56
    f32x4 s0 = (f32x4){0.f, 0.f, 0.f, 0.f};
    f32x4 s1 = (f32x4){0.f, 0.f, 0.f, 0.f};
#pragma unroll
    for (int u = 0; u < 8; ++u) {
      const f32x4 t0 = *(const f32x4*)&red[u * 4096 + jj * 64 + d0];
      const f32x4 t1 = *(const f32x4*)&red[u * 4096 + jj * 64 + d0 + 4];
      s0[0] += t0[0]; s0[1] += t0[1]; s0[2] += t0[2]; s0[3] += t0[3];
      s1[0] += t1[0]; s1[1] += t1[1]; s1[2] += t1[2]; s1[3] += t1[3];
    }
    *(f32x4*)(op + jj * 64 + d0) = s0;
    *(f32x4*)(op + jj * 64 + d0 + 4) = s1;
  }
}

// ---------------------------------------------------------------------------
extern "C" void kernel_launch(void* const* d_in, const int* in_sizes, int n_in,
                              void* d_out, int out_size, void* d_ws, size_t ws_size,
                              hipStream_t stream) {
  const float* q = (const float*)d_in[0];
  const float* k = (const float*)d_in[1];
  const float* v = (const float*)d_in[2];

  unsigned short* Qf = (unsigned short*)d_ws;
  unsigned short* Kf = Qf + NTOT;
  unsigned short* Vf = Kf + NTOT;
  float* part_ls = (float*)(Vf + NTOT);
  float* c2 = part_ls + (size_t)NJC * NROW;
  float* outp = (float*)d_out;

  prep_kernel<<<512, 256, 0, stream>>>(q, k, v, Qf, Kf, Vf);
  stats_kernel<<<1024, 256, 0, stream>>>(Qf, Kf, part_ls);
  logify_kernel<<<(int)(NROW / 256), 256, 0, stream>>>(part_ls, c2);
  attn_out_kernel<<<256, 512, 0, stream>>>(Qf, Kf, Vf, c2, outp);
}